// Round 21
// baseline (1798.959 us; speedup 1.0000x reference)
//
#include <hip/hip_runtime.h>
#include <cstdint>
#include <cstddef>

// ============================================================================
// ConditionalRBM sampler — bit-exact resimulation of the JAX reference.
//
// Round-21: R20's b64 read was a 4-way bank conflict (3.19M counts) — my
// "conflict-free" claim was wrong; R19 (1503us) stays best. Constraint
// mapping: tile geometry alone can't give 4-row reuse AND 4 waves/SIMD.
// Escape: 2 K-VALUES PER ds_read_b128 via a pre-interleaved W layout.
// A one-time prep kernel builds Q[k2][cp][4] = {W[2k2][2cp], W[2k2][2cp+1],
// W[2k2+1][2cp], W[2k2+1][2cp+1]} in GLOBAL memory (m173 pre-swizzle at
// array level), so gld_lds16's linear staging lands quads in LDS directly.
// R19 geometry kept (512 thr, rg=t>>7 wave-uniform 4 rows, 2 cols/thread,
// 4 waves/SIMD): per k-pair = 1 ds_read_b128 (clean stride-16B pattern) +
// 8 SALU selects + 16 fma. LDS/phase/CU 20.5 -> 10.2us; barriers 16 -> 8.
// Bit-exact: per-acc fma order = even k then odd k within a pair, pairs
// ascending -> strictly ascending k, single acc per output; epilogue/pack/
// RNG machinery verbatim from R20 (verified).
//
// ASSUMPTION STACK (verified bit-exact in earlier rounds):
//  A1: jax_threefry_partitionable = True:
//      split(key,n)[i] = TF(key,(0,i)); bits32[j] = TF0(key,(0,j)) ^ TF1(key,(0,j))
//  A2: logistic(x) = 1/(1+exp(-x)), IEEE fdiv
//  A3: exp = XLA-CPU vectorized Cephes/Eigen pexp
//  A4: dot = ascending-k single-accumulator fma chain (exact 0/1 products)
//  A5: x = (dot + udot) + bias association
//  Output dtype: int32 0/1 (harness reads d_out as int32).
//  Pack semantics (R12-verified): state word w of a row, bit b = col 32w+b.
// ============================================================================

#pragma clang fp contract(off)

#define BATCH 8192
#define NU 64
#define NF 256   // num_v == num_h == 256
#define RPB 16   // rows per block (chain kernel)
#define TPB 512  // threads per block (chain kernel) = 8 waves
#define CH 32    // k-rows per staged W chunk (= one 32-bit mask word)
#define NCH (NF / CH)   // 8 chunks per phase
#define RTI 16   // rows per block in k_udot
#define THERM 24
#define NSAMP 8
#define NSTEP (THERM + NSAMP)   // 32 Gibbs steps

// ---------------- Threefry-2x32 (JAX rotation/injection schedule) ----------
__host__ __device__ __forceinline__ void tf2x32(uint32_t k0, uint32_t k1,
                                                uint32_t x0, uint32_t x1,
                                                uint32_t* o0, uint32_t* o1) {
  uint32_t ks2 = k0 ^ k1 ^ 0x1BD11BDAu;
  x0 += k0; x1 += k1;
#define TFR(r) { x0 += x1; x1 = (x1 << (r)) | (x1 >> (32 - (r))); x1 ^= x0; }
  TFR(13) TFR(15) TFR(26) TFR(6)
  x0 += k1;  x1 += ks2 + 1u;
  TFR(17) TFR(29) TFR(16) TFR(24)
  x0 += ks2; x1 += k0 + 2u;
  TFR(13) TFR(15) TFR(26) TFR(6)
  x0 += k0;  x1 += k1 + 3u;
  TFR(17) TFR(29) TFR(16) TFR(24)
  x0 += k1;  x1 += ks2 + 4u;
  TFR(13) TFR(15) TFR(26) TFR(6)
  x0 += ks2; x1 += k0 + 5u;
#undef TFR
  *o0 = x0; *o1 = x1;
}

// ---------------- XLA-CPU expf (Cephes/Eigen polynomial) -------------------
__device__ __forceinline__ float xla_expf(float x) {
  float xc = fminf(x, 88.3762626647950f);
  xc = fmaxf(xc, -88.3762626647949f);
  float fx = floorf(__builtin_fmaf(xc, 1.44269504088896341f, 0.5f));
  float tmp = 0.693359375f * fx;          // separate rounding (contract off)
  float z = -2.12194440e-4f * fx;
  float r = xc - tmp;
  r = r - z;
  z = r * r;
  float y = __builtin_fmaf(r, 1.9875691500e-4f, 1.3981999507e-3f);
  y = __builtin_fmaf(y, r, 8.3334519073e-3f);
  y = __builtin_fmaf(y, r, 4.1665795894e-2f);
  y = __builtin_fmaf(y, r, 1.6666665459e-1f);
  y = __builtin_fmaf(y, r, 5.0000001201e-1f);
  y = __builtin_fmaf(y, z, r);
  y = y + 1.0f;
  int n = (int)fx;
  float p2 = __int_as_float((n + 127) << 23);
  float res = y * p2;
  return fmaxf(res, x);                   // Eigen pexp: pmax(res, original x)
}

__device__ __forceinline__ float sigmoid_ref(float x) {
  float e = xla_expf(-x);                 // negate exact
  return 1.0f / (1.0f + e);               // IEEE fdiv (no fast-math)
}

// bern: partitionable threefry bits -> uniform [0,1) -> (u < p)
__device__ __forceinline__ float bern_sample(uint32_t key0, uint32_t key1,
                                             uint32_t idx, float p) {
  uint32_t b0, b1;
  tf2x32(key0, key1, 0u, idx, &b0, &b1);  // counter = (hi=0, lo=flat_idx)
  uint32_t bits = b0 ^ b1;                // 32-bit path XORs both words
  float u = __uint_as_float((bits >> 9) | 0x3f800000u) - 1.0f;
  return (u < p) ? 1.0f : 0.0f;
}

// async global->LDS, 16 bytes per lane (linear layout: dest = base+lane*16)
__device__ __forceinline__ void gld_lds16(const float* g, float* l) {
  __builtin_amdgcn_global_load_lds(
      (const __attribute__((address_space(1))) void*)g,
      (__attribute__((address_space(3))) void*)l, 16, 0, 0);
}

// ---------------- kernels ---------------------------------------------------
__global__ void k_transpose(const float* __restrict__ Whv,
                            float* __restrict__ WhvT) {
  int j = threadIdx.x;  // hidden
  int k = blockIdx.x;   // visible
  WhvT[k * NF + j] = Whv[j * NF + k];
}

// Build quad-interleaved layout: Q[k2][cp] = {M[2k2][2cp], M[2k2][2cp+1],
// M[2k2+1][2cp], M[2k2+1][2cp+1]}  (M is k-major [256][256])
__global__ void k_quad(const float* __restrict__ M, float* __restrict__ Q) {
  const int idx = blockIdx.x * 256 + threadIdx.x;   // quad id in [0,16384)
  const int k2 = idx >> 7, cp = idx & 127;
  float4 q;
  q.x = M[(size_t)(2 * k2) * NF + 2 * cp];
  q.y = M[(size_t)(2 * k2) * NF + 2 * cp + 1];
  q.z = M[(size_t)(2 * k2 + 1) * NF + 2 * cp];
  q.w = M[(size_t)(2 * k2 + 1) * NF + 2 * cp + 1];
  ((float4*)Q)[idx] = q;
}

// out[row][j] = sum_k u[row][k] * W[j][k], ascending k (exact products).
__global__ __launch_bounds__(256, 2) void k_udot(const float* __restrict__ U,
                                                 const float* __restrict__ W,
                                                 float* __restrict__ out) {
  __shared__ __align__(16) float Ulds[NU * RTI];  // [k][i], 4 KiB
  const int j = threadIdx.x;
  const int i0 = blockIdx.x * RTI;
  const int si = j & 15;
  const int sg = j >> 4;
  {
    float4 u4 = *(const float4*)(U + (size_t)(i0 + si) * NU + sg * 4);
    Ulds[(sg * 4 + 0) * RTI + si] = u4.x;
    Ulds[(sg * 4 + 1) * RTI + si] = u4.y;
    Ulds[(sg * 4 + 2) * RTI + si] = u4.z;
    Ulds[(sg * 4 + 3) * RTI + si] = u4.w;
  }
  float wreg[NU];
  const float4* wr4 = (const float4*)(W + (size_t)j * NU);
#pragma unroll
  for (int r = 0; r < NU / 4; ++r) {
    float4 t = wr4[r];
    wreg[4 * r + 0] = t.x; wreg[4 * r + 1] = t.y;
    wreg[4 * r + 2] = t.z; wreg[4 * r + 3] = t.w;
  }
  __syncthreads();
  float acc[RTI];
#pragma unroll
  for (int i = 0; i < RTI; ++i) acc[i] = 0.0f;
#pragma unroll
  for (int kk = 0; kk < NU; ++kk) {
    const float w = wreg[kk];
    const float4 s0 = *(const float4*)(&Ulds[kk * RTI + 0]);
    const float4 s1 = *(const float4*)(&Ulds[kk * RTI + 4]);
    const float4 s2 = *(const float4*)(&Ulds[kk * RTI + 8]);
    const float4 s3 = *(const float4*)(&Ulds[kk * RTI + 12]);
    acc[0]  = __builtin_fmaf(s0.x, w, acc[0]);
    acc[1]  = __builtin_fmaf(s0.y, w, acc[1]);
    acc[2]  = __builtin_fmaf(s0.z, w, acc[2]);
    acc[3]  = __builtin_fmaf(s0.w, w, acc[3]);
    acc[4]  = __builtin_fmaf(s1.x, w, acc[4]);
    acc[5]  = __builtin_fmaf(s1.y, w, acc[5]);
    acc[6]  = __builtin_fmaf(s1.z, w, acc[6]);
    acc[7]  = __builtin_fmaf(s1.w, w, acc[7]);
    acc[8]  = __builtin_fmaf(s2.x, w, acc[8]);
    acc[9]  = __builtin_fmaf(s2.y, w, acc[9]);
    acc[10] = __builtin_fmaf(s2.z, w, acc[10]);
    acc[11] = __builtin_fmaf(s2.w, w, acc[11]);
    acc[12] = __builtin_fmaf(s3.x, w, acc[12]);
    acc[13] = __builtin_fmaf(s3.y, w, acc[13]);
    acc[14] = __builtin_fmaf(s3.z, w, acc[14]);
    acc[15] = __builtin_fmaf(s3.w, w, acc[15]);
  }
#pragma unroll
  for (int i = 0; i < RTI; ++i)
    out[(size_t)(i0 + i) * NF + j] = acc[i];   // row-major (coalesced)
}

// Whole Gibbs chain for 16 rows: init + 32 steps (h,v), samples to out.
// 512 threads = 8 waves; tile 4 rows x 2 cols; rg = t>>7 (wave-uniform),
// cgg = t&127 = this thread's col-pair; jc = 2*cgg.
// Qh/Qv: quad-interleaved W layouts (one b128 = 2k x 2cols).
__global__ __launch_bounds__(TPB, 4) void k_chain(
    const float* __restrict__ Qh, const float* __restrict__ Qv,
    const float* __restrict__ uh, const float* __restrict__ uv,
    const float* __restrict__ bh, const float* __restrict__ bv,
    int* __restrict__ out) {
  __shared__ __align__(16) float Wbuf[2][CH / 2 * NF * 2];  // 2 x 32 KiB
  __shared__ uint32_t bitsL[2][RPB * 8];             // [0]=v [1]=h, 1 KiB
  __shared__ uint32_t nib[RPB * 128];                // 8 KiB pack scratch
  __shared__ float biasL[2][NF];                     // [0]=bh [1]=bv, 2 KiB
  __shared__ uint32_t ksL[66];                       // 33 key pairs
  __shared__ uint32_t keysL[NSTEP * 4];              // (kh0,kh1,kv0,kv1)/step

  const int t = threadIdx.x;
  const int rowbase = blockIdx.x * RPB;
  const int rg = t >> 7;         // 4 row-groups x 4 rows (WAVE-UNIFORM)
  const int cgg = t & 127;       // 128 col-pairs
  const int jc = cgg * 2;        // thread's first col

  // per-thread C operands: 4 rows x 2 cols of uh and uv (coalesced loads)
  float2 cuh[4], cuv[4];
#pragma unroll
  for (int ri = 0; ri < 4; ++ri) {
    const int lr = rg * 4 + ri;
    cuh[ri] = *(const float2*)(uh + (size_t)(rowbase + lr) * NF + jc);
    cuv[ri] = *(const float2*)(uv + (size_t)(rowbase + lr) * NF + jc);
  }

  // ---- prologue: biases + key schedule ----
  if (t < NF) {
    biasL[0][t] = bh[t];
    biasL[1][t] = bv[t];
  }
  if (t < 33) tf2x32(0u, 1u, 0u, (uint32_t)t, &ksL[2 * t], &ksL[2 * t + 1]);
  __syncthreads();
  if (t < NSTEP) {
    uint32_t a = ksL[2 * (1 + t)], b2 = ksL[2 * (1 + t) + 1];
    tf2x32(a, b2, 0u, 0u, &keysL[4 * t + 0], &keysL[4 * t + 1]);
    tf2x32(a, b2, 0u, 1u, &keysL[4 * t + 2], &keysL[4 * t + 3]);
  }
  __syncthreads();

  // ---- init: v0 = bern(ks[0], sigmoid(uv + bv)) -> bitsL[0] ----
  {
    const uint32_t k0 = ksL[0], k1 = ksL[1];
    const float2 b2 = *(const float2*)(&biasL[1][jc]);
#pragma unroll
    for (int ri = 0; ri < 4; ++ri) {
      const int lr = rg * 4 + ri;
      const int row = rowbase + lr;
      const uint32_t idx0 = (uint32_t)(row * NF + jc);
      uint32_t nb = 0;
      nb |= (bern_sample(k0, k1, idx0 + 0,
                 sigmoid_ref(cuv[ri].x + b2.x)) != 0.0f ? 1u : 0u);
      nb |= (bern_sample(k0, k1, idx0 + 1,
                 sigmoid_ref(cuv[ri].y + b2.y)) != 0.0f ? 2u : 0u);
      nib[lr * 128 + cgg] = nb;
    }
  }
  __syncthreads();
  if (t < 128) {
    const int lr = t >> 3, wo = t & 7;
    const uint32_t* nn = &nib[lr * 128 + wo * 16];
    uint32_t wrd = 0;
#pragma unroll
    for (int g = 0; g < 16; ++g) wrd |= nn[g] << (2 * g);
    bitsL[0][lr * 8 + wo] = wrd;
  }
  __syncthreads();

  // ---- Gibbs chain: 32 steps x (h-phase, v-phase) ----
#pragma unroll 1
  for (int tt = 0; tt < NSTEP; ++tt) {
#pragma unroll 1
    for (int ph = 0; ph < 2; ++ph) {
      const float* Q = ph ? Qv : Qh;             // quad layout for this phase
      const uint32_t* sb = bitsL[ph];            // ph=0 reads v, ph=1 reads h
      uint32_t* db = bitsL[ph ^ 1];
      const float* bl = biasL[ph];
      const uint32_t k0 = keysL[4 * tt + 2 * ph + 0];
      const uint32_t k1 = keysL[4 * tt + 2 * ph + 1];
      int* smp = (ph == 1 && tt >= THERM)
                     ? out + (size_t)(tt - THERM) * BATCH * NF
                     : (int*)nullptr;

      float acc[8];                  // acc[ri*2+ci], ri in 0..3
#pragma unroll
      for (int q = 0; q < 8; ++q) acc[q] = 0.0f;

      // stage chunk 0 (32 KiB): 4 passes x 512 thr x 16B, async, no regs
#pragma unroll
      for (int q = 0; q < 4; ++q)
        gld_lds16(Q + (size_t)(q * TPB + t) * 4, &Wbuf[0][(q * TPB + t) * 4]);
      __syncthreads();   // drains vmcnt -> chunk 0 landed

#pragma unroll 1
      for (int c = 0; c < NCH; ++c) {            // chunk c = mask word c
        if (c + 1 < NCH) {                       // prefetch next chunk
          const float* src = Q + (size_t)(c + 1) * (CH * NF);
          float* dst = Wbuf[(c + 1) & 1];
#pragma unroll
          for (int q = 0; q < 4; ++q)
            gld_lds16(src + (size_t)(q * TPB + t) * 4,
                      &dst[(q * TPB + t) * 4]);
        }
        // wave-uniform mask words -> SGPRs (scalar pipe does the selects)
        const uint32_t wd0 =
            __builtin_amdgcn_readfirstlane(sb[(rg * 4 + 0) * 8 + c]);
        const uint32_t wd1 =
            __builtin_amdgcn_readfirstlane(sb[(rg * 4 + 1) * 8 + c]);
        const uint32_t wd2 =
            __builtin_amdgcn_readfirstlane(sb[(rg * 4 + 2) * 8 + c]);
        const uint32_t wd3 =
            __builtin_amdgcn_readfirstlane(sb[(rg * 4 + 3) * 8 + c]);
        const float* wl = &Wbuf[c & 1][cgg * 4];
#pragma unroll
        for (int kk2 = 0; kk2 < CH / 2; ++kk2) { // k-pair: k = c*32 + 2*kk2
          // quad: {W[k][j], W[k][j+1], W[k+1][j], W[k+1][j+1]}
          const float4 w = *(const float4*)(wl + (size_t)kk2 * 512);
          const float sa0 = (wd0 & (1u << (2 * kk2))) ? 1.0f : 0.0f;  // k
          const float sa1 = (wd1 & (1u << (2 * kk2))) ? 1.0f : 0.0f;
          const float sa2 = (wd2 & (1u << (2 * kk2))) ? 1.0f : 0.0f;
          const float sa3 = (wd3 & (1u << (2 * kk2))) ? 1.0f : 0.0f;
          const float sb0 = (wd0 & (2u << (2 * kk2))) ? 1.0f : 0.0f;  // k+1
          const float sb1 = (wd1 & (2u << (2 * kk2))) ? 1.0f : 0.0f;
          const float sb2 = (wd2 & (2u << (2 * kk2))) ? 1.0f : 0.0f;
          const float sb3 = (wd3 & (2u << (2 * kk2))) ? 1.0f : 0.0f;
          // even k first, then odd k: each acc sees strictly ascending k
          acc[0] = __builtin_fmaf(sa0, w.x, acc[0]);
          acc[1] = __builtin_fmaf(sa0, w.y, acc[1]);
          acc[2] = __builtin_fmaf(sa1, w.x, acc[2]);
          acc[3] = __builtin_fmaf(sa1, w.y, acc[3]);
          acc[4] = __builtin_fmaf(sa2, w.x, acc[4]);
          acc[5] = __builtin_fmaf(sa2, w.y, acc[5]);
          acc[6] = __builtin_fmaf(sa3, w.x, acc[6]);
          acc[7] = __builtin_fmaf(sa3, w.y, acc[7]);
          acc[0] = __builtin_fmaf(sb0, w.z, acc[0]);
          acc[1] = __builtin_fmaf(sb0, w.w, acc[1]);
          acc[2] = __builtin_fmaf(sb1, w.z, acc[2]);
          acc[3] = __builtin_fmaf(sb1, w.w, acc[3]);
          acc[4] = __builtin_fmaf(sb2, w.z, acc[4]);
          acc[5] = __builtin_fmaf(sb2, w.w, acc[5]);
          acc[6] = __builtin_fmaf(sb3, w.z, acc[6]);
          acc[7] = __builtin_fmaf(sb3, w.w, acc[7]);
        }
        __syncthreads();   // chunk c+1 landed; all done reading buf[c&1]
      }

      // epilogue: x = (dot + udot) + bias ; sigmoid ; bern ; pack bits
      const float2 b2 = *(const float2*)(bl + jc);
#pragma unroll
      for (int ri = 0; ri < 4; ++ri) {
        const int lr = rg * 4 + ri;
        const int row = rowbase + lr;
        const float2 c2 = ph ? cuv[ri] : cuh[ri];   // static idx, uniform ph
        const uint32_t idx0 = (uint32_t)(row * NF + jc);
        const float v0 = bern_sample(k0, k1, idx0 + 0,
            sigmoid_ref((acc[ri * 2 + 0] + c2.x) + b2.x));
        const float v1 = bern_sample(k0, k1, idx0 + 1,
            sigmoid_ref((acc[ri * 2 + 1] + c2.y) + b2.y));
        nib[lr * 128 + cgg] = (v0 != 0.0f ? 1u : 0u) |
                              (v1 != 0.0f ? 2u : 0u);
        if (smp) {
          int2 o;
          o.x = (v0 != 0.0f) ? 1 : 0;
          o.y = (v1 != 0.0f) ? 1 : 0;
          *(int2*)(smp + (size_t)row * NF + jc) = o;
        }
      }
      __syncthreads();
      if (t < 128) {                 // assemble 2 words per row
        const int lr = t >> 3, wo = t & 7;
        const uint32_t* nn = &nib[lr * 128 + wo * 16];
        uint32_t wrd = 0;
#pragma unroll
        for (int g = 0; g < 16; ++g) wrd |= nn[g] << (2 * g);
        db[lr * 8 + wo] = wrd;
      }
      __syncthreads();
    }
  }
}

// ---------------- launch ----------------------------------------------------
extern "C" void kernel_launch(void* const* d_in, const int* in_sizes, int n_in,
                              void* d_out, int out_size, void* d_ws, size_t ws_size,
                              hipStream_t stream) {
  const float* u_state = (const float*)d_in[0];  // [8192][64] 0/1 floats
  const float* Wvu     = (const float*)d_in[1];  // [256][64]
  const float* Whu     = (const float*)d_in[2];  // [256][64]
  const float* Whv     = (const float*)d_in[3];  // [256][256]
  const float* bv      = (const float*)d_in[4];  // [256]
  const float* bh      = (const float*)d_in[5];  // [256]
  int* out = (int*)d_out;                        // [8][8192][256] as int32 0/1

  // workspace: WhvT + Qh + Qv (256KB each) + uh 8MB + uv 8MB ≈ 17.5 MB
  float* ws   = (float*)d_ws;
  float* WhvT = ws;                          // 65536 f
  float* Qh   = WhvT + NF * NF;              // 65536 f (quad of WhvT)
  float* Qv   = Qh + NF * NF;                // 65536 f (quad of Whv)
  float* uh   = Qv + NF * NF;                // [8192][256]
  float* uv   = uh + (size_t)BATCH * NF;

  k_transpose<<<NF, NF, 0, stream>>>(Whv, WhvT);
  k_quad<<<64, 256, 0, stream>>>(WhvT, Qh);   // h-phase quads
  k_quad<<<64, 256, 0, stream>>>(Whv, Qv);    // v-phase quads
  k_udot<<<BATCH / RTI, NF, 0, stream>>>(u_state, Whu, uh);   // u @ Whu.T
  k_udot<<<BATCH / RTI, NF, 0, stream>>>(u_state, Wvu, uv);   // u @ Wvu.T
  // whole Gibbs chain in ONE launch (row-independent blocks), 8 waves/block
  k_chain<<<BATCH / RPB, TPB, 0, stream>>>(Qh, Qv, uh, uv, bh, bv, out);

  (void)in_sizes; (void)n_in; (void)out_size; (void)ws_size;
}

// Round 22
// 1439.985 us; speedup vs baseline: 1.2493x; 1.2493x over previous
//
#include <hip/hip_runtime.h>
#include <cstdint>
#include <cstddef>

// ============================================================================
// ConditionalRBM sampler — bit-exact resimulation of the JAX reference.
//
// Round-22: R20/R21 (higher W-reuse layouts) both regressed; R19 = proven
// best (1503us) at ~93% of its LDS-delivery bound (16 waves/CU x 256
// ds_read_b128 x 12cy = 20.5us/phase vs 22.0 measured). This round cuts LDS
// INSTRUCTIONS with zero layout change: the two row-bits per k live in
// SGPRs; when both are 0 the k-step contributes exactly nothing -> skip
// {ds_read_b128 + 8 fma} behind a WAVE-UNIFORM s_cbranch (P~25%).
// Bit-exact: reference does acc=fma(0,w,acc); 0*w=+/-0 and +/-0+acc = acc
// for all reachable acc (acc never -0: starts +0, +0+(+/-0)=+0, exact
// cancellation rounds to +0) -> eliding is bit-identical. Executed k's
// unchanged (same selects, same ascending-k single-acc chains).
// Everything else verbatim from R19 (best, verified).
//
// ASSUMPTION STACK (verified bit-exact in earlier rounds):
//  A1: jax_threefry_partitionable = True:
//      split(key,n)[i] = TF(key,(0,i)); bits32[j] = TF0(key,(0,j)) ^ TF1(key,(0,j))
//  A2: logistic(x) = 1/(1+exp(-x)), IEEE fdiv
//  A3: exp = XLA-CPU vectorized Cephes/Eigen pexp
//  A4: dot = ascending-k single-accumulator fma chain (exact 0/1 products)
//  A5: x = (dot + udot) + bias association
//  Output dtype: int32 0/1 (harness reads d_out as int32).
//  Pack semantics (R12-verified): state word w of a row, bit b = col 32w+b.
// ============================================================================

#pragma clang fp contract(off)

#define BATCH 8192
#define NU 64
#define NF 256   // num_v == num_h == 256
#define RPB 16   // rows per block (chain kernel)
#define TPB 512  // threads per block (chain kernel) = 8 waves
#define CH 16    // m-rows per staged W chunk
#define NCH (NF / CH)   // 16 chunks per phase
#define RTI 16   // rows per block in k_udot
#define THERM 24
#define NSAMP 8
#define NSTEP (THERM + NSAMP)   // 32 Gibbs steps

// ---------------- Threefry-2x32 (JAX rotation/injection schedule) ----------
__host__ __device__ __forceinline__ void tf2x32(uint32_t k0, uint32_t k1,
                                                uint32_t x0, uint32_t x1,
                                                uint32_t* o0, uint32_t* o1) {
  uint32_t ks2 = k0 ^ k1 ^ 0x1BD11BDAu;
  x0 += k0; x1 += k1;
#define TFR(r) { x0 += x1; x1 = (x1 << (r)) | (x1 >> (32 - (r))); x1 ^= x0; }
  TFR(13) TFR(15) TFR(26) TFR(6)
  x0 += k1;  x1 += ks2 + 1u;
  TFR(17) TFR(29) TFR(16) TFR(24)
  x0 += ks2; x1 += k0 + 2u;
  TFR(13) TFR(15) TFR(26) TFR(6)
  x0 += k0;  x1 += k1 + 3u;
  TFR(17) TFR(29) TFR(16) TFR(24)
  x0 += k1;  x1 += ks2 + 4u;
  TFR(13) TFR(15) TFR(26) TFR(6)
  x0 += ks2; x1 += k0 + 5u;
#undef TFR
  *o0 = x0; *o1 = x1;
}

// ---------------- XLA-CPU expf (Cephes/Eigen polynomial) -------------------
__device__ __forceinline__ float xla_expf(float x) {
  float xc = fminf(x, 88.3762626647950f);
  xc = fmaxf(xc, -88.3762626647949f);
  float fx = floorf(__builtin_fmaf(xc, 1.44269504088896341f, 0.5f));
  float tmp = 0.693359375f * fx;          // separate rounding (contract off)
  float z = -2.12194440e-4f * fx;
  float r = xc - tmp;
  r = r - z;
  z = r * r;
  float y = __builtin_fmaf(r, 1.9875691500e-4f, 1.3981999507e-3f);
  y = __builtin_fmaf(y, r, 8.3334519073e-3f);
  y = __builtin_fmaf(y, r, 4.1665795894e-2f);
  y = __builtin_fmaf(y, r, 1.6666665459e-1f);
  y = __builtin_fmaf(y, r, 5.0000001201e-1f);
  y = __builtin_fmaf(y, z, r);
  y = y + 1.0f;
  int n = (int)fx;
  float p2 = __int_as_float((n + 127) << 23);
  float res = y * p2;
  return fmaxf(res, x);                   // Eigen pexp: pmax(res, original x)
}

__device__ __forceinline__ float sigmoid_ref(float x) {
  float e = xla_expf(-x);                 // negate exact
  return 1.0f / (1.0f + e);               // IEEE fdiv (no fast-math)
}

// bern: partitionable threefry bits -> uniform [0,1) -> (u < p)
__device__ __forceinline__ float bern_sample(uint32_t key0, uint32_t key1,
                                             uint32_t idx, float p) {
  uint32_t b0, b1;
  tf2x32(key0, key1, 0u, idx, &b0, &b1);  // counter = (hi=0, lo=flat_idx)
  uint32_t bits = b0 ^ b1;                // 32-bit path XORs both words
  float u = __uint_as_float((bits >> 9) | 0x3f800000u) - 1.0f;
  return (u < p) ? 1.0f : 0.0f;
}

// async global->LDS, 16 bytes per lane (linear layout: dest = base+lane*16)
__device__ __forceinline__ void gld_lds16(const float* g, float* l) {
  __builtin_amdgcn_global_load_lds(
      (const __attribute__((address_space(1))) void*)g,
      (__attribute__((address_space(3))) void*)l, 16, 0, 0);
}

// ---------------- kernels ---------------------------------------------------
__global__ void k_transpose(const float* __restrict__ Whv,
                            float* __restrict__ WhvT) {
  int j = threadIdx.x;  // hidden
  int k = blockIdx.x;   // visible
  WhvT[k * NF + j] = Whv[j * NF + k];
}

// out[row][j] = sum_k u[row][k] * W[j][k], ascending k (exact products).
__global__ __launch_bounds__(256, 2) void k_udot(const float* __restrict__ U,
                                                 const float* __restrict__ W,
                                                 float* __restrict__ out) {
  __shared__ __align__(16) float Ulds[NU * RTI];  // [k][i], 4 KiB
  const int j = threadIdx.x;
  const int i0 = blockIdx.x * RTI;
  const int si = j & 15;
  const int sg = j >> 4;
  {
    float4 u4 = *(const float4*)(U + (size_t)(i0 + si) * NU + sg * 4);
    Ulds[(sg * 4 + 0) * RTI + si] = u4.x;
    Ulds[(sg * 4 + 1) * RTI + si] = u4.y;
    Ulds[(sg * 4 + 2) * RTI + si] = u4.z;
    Ulds[(sg * 4 + 3) * RTI + si] = u4.w;
  }
  float wreg[NU];
  const float4* wr4 = (const float4*)(W + (size_t)j * NU);
#pragma unroll
  for (int r = 0; r < NU / 4; ++r) {
    float4 t = wr4[r];
    wreg[4 * r + 0] = t.x; wreg[4 * r + 1] = t.y;
    wreg[4 * r + 2] = t.z; wreg[4 * r + 3] = t.w;
  }
  __syncthreads();
  float acc[RTI];
#pragma unroll
  for (int i = 0; i < RTI; ++i) acc[i] = 0.0f;
#pragma unroll
  for (int kk = 0; kk < NU; ++kk) {
    const float w = wreg[kk];
    const float4 s0 = *(const float4*)(&Ulds[kk * RTI + 0]);
    const float4 s1 = *(const float4*)(&Ulds[kk * RTI + 4]);
    const float4 s2 = *(const float4*)(&Ulds[kk * RTI + 8]);
    const float4 s3 = *(const float4*)(&Ulds[kk * RTI + 12]);
    acc[0]  = __builtin_fmaf(s0.x, w, acc[0]);
    acc[1]  = __builtin_fmaf(s0.y, w, acc[1]);
    acc[2]  = __builtin_fmaf(s0.z, w, acc[2]);
    acc[3]  = __builtin_fmaf(s0.w, w, acc[3]);
    acc[4]  = __builtin_fmaf(s1.x, w, acc[4]);
    acc[5]  = __builtin_fmaf(s1.y, w, acc[5]);
    acc[6]  = __builtin_fmaf(s1.z, w, acc[6]);
    acc[7]  = __builtin_fmaf(s1.w, w, acc[7]);
    acc[8]  = __builtin_fmaf(s2.x, w, acc[8]);
    acc[9]  = __builtin_fmaf(s2.y, w, acc[9]);
    acc[10] = __builtin_fmaf(s2.z, w, acc[10]);
    acc[11] = __builtin_fmaf(s2.w, w, acc[11]);
    acc[12] = __builtin_fmaf(s3.x, w, acc[12]);
    acc[13] = __builtin_fmaf(s3.y, w, acc[13]);
    acc[14] = __builtin_fmaf(s3.z, w, acc[14]);
    acc[15] = __builtin_fmaf(s3.w, w, acc[15]);
  }
#pragma unroll
  for (int i = 0; i < RTI; ++i)
    out[(size_t)(i0 + i) * NF + j] = acc[i];   // row-major (coalesced)
}

// Whole Gibbs chain for 16 rows: init + 32 steps (h,v), samples to out.
// 512 threads = 8 waves; wave owns 2 rows (rg = t>>6), lanes cover 256 cols.
__global__ __launch_bounds__(TPB, 4) void k_chain(
    const float* __restrict__ Whv, const float* __restrict__ WhvT,
    const float* __restrict__ uh, const float* __restrict__ uv,
    const float* __restrict__ bh, const float* __restrict__ bv,
    int* __restrict__ out) {
  __shared__ __align__(16) float Wbuf[2][CH * NF];   // 2 x 16 KiB
  __shared__ uint32_t bitsL[2][RPB * 8];             // [0]=v [1]=h, 1 KiB
  __shared__ uint32_t nib[RPB * 64];                 // 4 KiB pack scratch
  __shared__ float biasL[2][NF];                     // [0]=bh [1]=bv, 2 KiB
  __shared__ uint32_t ksL[66];                       // 33 key pairs
  __shared__ uint32_t keysL[NSTEP * 4];              // (kh0,kh1,kv0,kv1)/step

  const int t = threadIdx.x;
  const int rowbase = blockIdx.x * RPB;
  const int rg = t >> 6;         // wave id (0..7) -> rows {2rg, 2rg+1}
  const int cgg = t & 63;        // 64 col-groups x 4 cols
  const int jc = cgg * 4;        // thread's first col

  // per-thread C operands: 2 rows x 4 cols of uh and uv (coalesced loads)
  float4 cuh[2], cuv[2];
#pragma unroll
  for (int ri = 0; ri < 2; ++ri) {
    const int lr = rg * 2 + ri;
    cuh[ri] = *(const float4*)(uh + (size_t)(rowbase + lr) * NF + jc);
    cuv[ri] = *(const float4*)(uv + (size_t)(rowbase + lr) * NF + jc);
  }

  // ---- prologue: biases + key schedule ----
  if (t < NF) {
    biasL[0][t] = bh[t];
    biasL[1][t] = bv[t];
  }
  if (t < 33) tf2x32(0u, 1u, 0u, (uint32_t)t, &ksL[2 * t], &ksL[2 * t + 1]);
  __syncthreads();
  if (t < NSTEP) {
    uint32_t a = ksL[2 * (1 + t)], b2 = ksL[2 * (1 + t) + 1];
    tf2x32(a, b2, 0u, 0u, &keysL[4 * t + 0], &keysL[4 * t + 1]);
    tf2x32(a, b2, 0u, 1u, &keysL[4 * t + 2], &keysL[4 * t + 3]);
  }
  __syncthreads();

  // ---- init: v0 = bern(ks[0], sigmoid(uv + bv)) -> bitsL[0] ----
  {
    const uint32_t k0 = ksL[0], k1 = ksL[1];
#pragma unroll
    for (int ri = 0; ri < 2; ++ri) {
      const int lr = rg * 2 + ri;
      const int row = rowbase + lr;
      const float4 b4 = *(const float4*)(&biasL[1][jc]);
      const uint32_t idx0 = (uint32_t)(row * NF + jc);
      uint32_t nb = 0;
      nb |= (bern_sample(k0, k1, idx0 + 0,
                 sigmoid_ref(cuv[ri].x + b4.x)) != 0.0f ? 1u : 0u);
      nb |= (bern_sample(k0, k1, idx0 + 1,
                 sigmoid_ref(cuv[ri].y + b4.y)) != 0.0f ? 2u : 0u);
      nb |= (bern_sample(k0, k1, idx0 + 2,
                 sigmoid_ref(cuv[ri].z + b4.z)) != 0.0f ? 4u : 0u);
      nb |= (bern_sample(k0, k1, idx0 + 3,
                 sigmoid_ref(cuv[ri].w + b4.w)) != 0.0f ? 8u : 0u);
      nib[lr * 64 + cgg] = nb;
    }
  }
  __syncthreads();
  if (t < 128) {
    const int lr = t >> 3, wo = t & 7;
    const uint32_t* nn = &nib[lr * 64 + wo * 8];
    uint32_t wrd = 0;
#pragma unroll
    for (int g = 0; g < 8; ++g) wrd |= nn[g] << (4 * g);
    bitsL[0][lr * 8 + wo] = wrd;
  }
  __syncthreads();

  // ---- Gibbs chain: 32 steps x (h-phase, v-phase) ----
#pragma unroll 1
  for (int tt = 0; tt < NSTEP; ++tt) {
#pragma unroll 1
    for (int ph = 0; ph < 2; ++ph) {
      const float* M = ph ? Whv : WhvT;          // reduction index = M row
      const uint32_t* sb = bitsL[ph];            // ph=0 reads v, ph=1 reads h
      uint32_t* db = bitsL[ph ^ 1];
      const float* bl = biasL[ph];
      const uint32_t k0 = keysL[4 * tt + 2 * ph + 0];
      const uint32_t k1 = keysL[4 * tt + 2 * ph + 1];
      int* smp = (ph == 1 && tt >= THERM)
                     ? out + (size_t)(tt - THERM) * BATCH * NF
                     : (int*)nullptr;

      float acc[8];                  // acc[ri*4+ci], ri in {0,1}
#pragma unroll
      for (int q = 0; q < 8; ++q) acc[q] = 0.0f;

      // stage chunk 0 (async, no registers): 512 thr x 2 x 16B = 16 KiB
#pragma unroll
      for (int q = 0; q < 2; ++q)
        gld_lds16(M + (size_t)(q * TPB + t) * 4, &Wbuf[0][(q * TPB + t) * 4]);
      __syncthreads();   // drains vmcnt -> chunk 0 landed

#pragma unroll 1
      for (int c = 0; c < NCH; ++c) {
        if (c + 1 < NCH) {                       // prefetch next chunk
          const float* src = M + (size_t)(c + 1) * CH * NF;
          float* dst = Wbuf[(c + 1) & 1];
#pragma unroll
          for (int q = 0; q < 2; ++q)
            gld_lds16(src + (size_t)(q * TPB + t) * 4,
                      &dst[(q * TPB + t) * 4]);
        }
        const int wi = c >> 1;
        const int hs = (c & 1) * 16;             // which half of the word
        // wave-uniform mask words -> SGPRs (scalar pipe does the selects)
        const uint32_t wd0 =
            __builtin_amdgcn_readfirstlane(sb[(rg * 2 + 0) * 8 + wi]) >> hs;
        const uint32_t wd1 =
            __builtin_amdgcn_readfirstlane(sb[(rg * 2 + 1) * 8 + wi]) >> hs;
        const uint32_t wdo = wd0 | wd1;          // any-bit mask (scalar)
        const float* wl = &Wbuf[c & 1][jc];
#pragma unroll
        for (int kk = 0; kk < CH; ++kk) {        // m = c*16+kk, ascending
          // wave-uniform ZERO-SKIP: both row-bits 0 -> k contributes
          // exactly +/-0 to every acc -> eliding is bit-identical.
          if (wdo & (1u << kk)) {
            const float4 w = *(const float4*)(wl + kk * NF);
            const float s0 = (wd0 & (1u << kk)) ? 1.0f : 0.0f;  // SALU sel
            const float s1 = (wd1 & (1u << kk)) ? 1.0f : 0.0f;
            acc[0] = __builtin_fmaf(s0, w.x, acc[0]);    // exact products
            acc[1] = __builtin_fmaf(s0, w.y, acc[1]);
            acc[2] = __builtin_fmaf(s0, w.z, acc[2]);
            acc[3] = __builtin_fmaf(s0, w.w, acc[3]);
            acc[4] = __builtin_fmaf(s1, w.x, acc[4]);
            acc[5] = __builtin_fmaf(s1, w.y, acc[5]);
            acc[6] = __builtin_fmaf(s1, w.z, acc[6]);
            acc[7] = __builtin_fmaf(s1, w.w, acc[7]);
          }
        }
        __syncthreads();   // chunk c+1 landed; all done reading buf[c&1]
      }

      // epilogue: x = (dot + udot) + bias ; sigmoid ; bern ; pack bits
      const float4 b4 = *(const float4*)(bl + jc);
#pragma unroll
      for (int ri = 0; ri < 2; ++ri) {
        const int lr = rg * 2 + ri;
        const int row = rowbase + lr;
        const float4 c4 = ph ? cuv[ri] : cuh[ri];   // static idx, uniform ph
        const uint32_t idx0 = (uint32_t)(row * NF + jc);
        const float v0 = bern_sample(k0, k1, idx0 + 0,
            sigmoid_ref((acc[ri * 4 + 0] + c4.x) + b4.x));
        const float v1 = bern_sample(k0, k1, idx0 + 1,
            sigmoid_ref((acc[ri * 4 + 1] + c4.y) + b4.y));
        const float v2 = bern_sample(k0, k1, idx0 + 2,
            sigmoid_ref((acc[ri * 4 + 2] + c4.z) + b4.z));
        const float v3 = bern_sample(k0, k1, idx0 + 3,
            sigmoid_ref((acc[ri * 4 + 3] + c4.w) + b4.w));
        nib[lr * 64 + cgg] = (v0 != 0.0f ? 1u : 0u) |
                             (v1 != 0.0f ? 2u : 0u) |
                             (v2 != 0.0f ? 4u : 0u) |
                             (v3 != 0.0f ? 8u : 0u);
        if (smp) {
          int4 o;
          o.x = (v0 != 0.0f) ? 1 : 0;
          o.y = (v1 != 0.0f) ? 1 : 0;
          o.z = (v2 != 0.0f) ? 1 : 0;
          o.w = (v3 != 0.0f) ? 1 : 0;
          *(int4*)(smp + (size_t)row * NF + jc) = o;
        }
      }
      __syncthreads();
      if (t < 128) {                 // assemble 2 words per row
        const int lr = t >> 3, wo = t & 7;
        const uint32_t* nn = &nib[lr * 64 + wo * 8];
        uint32_t wrd = 0;
#pragma unroll
        for (int g = 0; g < 8; ++g) wrd |= nn[g] << (4 * g);
        db[lr * 8 + wo] = wrd;
      }
      __syncthreads();
    }
  }
}

// ---------------- launch ----------------------------------------------------
extern "C" void kernel_launch(void* const* d_in, const int* in_sizes, int n_in,
                              void* d_out, int out_size, void* d_ws, size_t ws_size,
                              hipStream_t stream) {
  const float* u_state = (const float*)d_in[0];  // [8192][64] 0/1 floats
  const float* Wvu     = (const float*)d_in[1];  // [256][64]
  const float* Whu     = (const float*)d_in[2];  // [256][64]
  const float* Whv     = (const float*)d_in[3];  // [256][256]
  const float* bv      = (const float*)d_in[4];  // [256]
  const float* bh      = (const float*)d_in[5];  // [256]
  int* out = (int*)d_out;                        // [8][8192][256] as int32 0/1

  // workspace: WhvT 256KB + uh 8MB + uv 8MB = ~16.8 MB
  float* ws   = (float*)d_ws;
  float* WhvT = ws;                          // 65536 f
  float* uh   = WhvT + NF * NF;              // [8192][256]
  float* uv   = uh + (size_t)BATCH * NF;

  k_transpose<<<NF, NF, 0, stream>>>(Whv, WhvT);
  k_udot<<<BATCH / RTI, NF, 0, stream>>>(u_state, Whu, uh);   // u @ Whu.T
  k_udot<<<BATCH / RTI, NF, 0, stream>>>(u_state, Wvu, uv);   // u @ Wvu.T
  // whole Gibbs chain in ONE launch (row-independent blocks), 8 waves/block
  k_chain<<<BATCH / RPB, TPB, 0, stream>>>(Whv, WhvT, uh, uv, bh, bv, out);

  (void)in_sizes; (void)n_in; (void)out_size; (void)ws_size;
}